// Round 8
// baseline (466.026 us; speedup 1.0000x reference)
//
#include <hip/hip_runtime.h>

typedef _Float16 half8_t __attribute__((ext_vector_type(8)));
typedef _Float16 half4_t __attribute__((ext_vector_type(4)));
typedef float floatx4 __attribute__((ext_vector_type(4)));
typedef float f32x16 __attribute__((ext_vector_type(16)));

// async global->LDS, 16B per lane. lds ptr wave-uniform; HW writes lane L at
// ldsbase + L*16.
__device__ inline void gload16(const void* g, void* l) {
  __builtin_amdgcn_global_load_lds(
      (const __attribute__((address_space(1))) unsigned int*)g,
      (__attribute__((address_space(3))) unsigned int*)l, 16, 0, 0);
}

// ===== 128x128 BT GEMM, 32x32x16 MFMA, coalesced staging, 2 blocks/CU =====
// C[m,n] = sum_h A[m,h]*B[n,h] (+bias). K=1024 = 16 tiles of BK=64.
// 256 threads = 4 waves in 2(wr) x 2(wc); per-wave C slice 64x64.
// LDS 64 KiB total (A: p*16384, B: 32768 + p*16384) -> 2 RESIDENT BLOCKS/CU.
// That cross-block overlap (m97/m114 mechanism) is the point: every drain /
// barrier stall of one block is filled by the other block's MFMA/LDS work.
//
// LDS layout per operand per parity (16 KB = 1024 x 16B chunks):
//   slot(m, kb) = m*8 + (kb ^ (m&7)), kb = k/8  [XOR involution both sides]
// Staging coalesced (r7): instr (wid,j) covers chunks c0..c0+63,
// c0 = (wid*4+j)*64; lane L -> row c0/8 + L/8, kb = (L&7)^(L/8); 8-lane
// groups read one aligned 128B row segment. laneoff = (L>>3)*ld+((L&7)^(L>>3))*8.
// Frag reads: slot xk[ks] = (ks*2+hi) ^ (lo&7); 4-way bank conflict (~1.58x)
// accepted (measured ~11% at r7).
//
// Per K-tile t (p=t&1, q=p^1): [stage A,B of t+1 -> q (8 gload16)]
// [read 16 frags from p] [lgkmcnt(0)] [16 MFMA] [vmcnt(0)] [barrier].
// One barrier/tile; stages write q while reads hit p (disjoint) -> race-free.
// vmcnt(0) residual drain is hidden by the co-resident block.
constexpr int NT = 16;  // K / 64

__device__ inline void lda_frags(const char* sA, int rb, const int* xk,
                                 half8_t af[2][4]) {
#pragma unroll
  for (int mp = 0; mp < 2; ++mp)
#pragma unroll
    for (int ks = 0; ks < 4; ++ks)
      af[mp][ks] = *(const half8_t*)(
          sA + (size_t)((rb + mp * 32) * 128 + xk[ks] * 16));
}

__device__ inline void ldb_frags(const char* sB, int cb, const int* xk,
                                 half8_t bf[2][4]) {
#pragma unroll
  for (int np = 0; np < 2; ++np)
#pragma unroll
    for (int ks = 0; ks < 4; ++ks)
      bf[np][ks] = *(const half8_t*)(
          sB + (size_t)((cb + np * 32) * 128 + xk[ks] * 16));
}

// stage one 128x64 operand K-tile u into parity-resolved base (4 gload16).
__device__ inline void stage_op(const _Float16* __restrict__ X, long laneoff,
                                int ldx, int u, char* opbase, int wid) {
#pragma unroll
  for (int j = 0; j < 4; ++j) {
    const int c0 = (wid * 4 + j) * 64;
    gload16(X + (long)(c0 >> 3) * ldx + u * 64 + laneoff,
            opbase + (size_t)c0 * 16);
  }
}

template <typename OT, int BIAS, int GX, int GY>
__global__ __launch_bounds__(256) void gemm128(
    const _Float16* __restrict__ A, long As, int lda,
    const _Float16* __restrict__ B, long Bs, int ldb,
    OT* __restrict__ C, long Cs, int ldc, const float* __restrict__ bias,
    int biasStride) {
  __shared__ char smem[65536];  // A: p*16384, B: 32768 + p*16384

  // XCD chunk swizzle (grids 1024/2048, always %8==0)
  const int id = blockIdx.x;
  const int chunk = gridDim.x >> 3;
  const int nid = (id & 7) * chunk + (id >> 3);
  const int bx = nid % GX;
  const int by = (nid / GX) % GY;
  const int bz = nid / (GX * GY);

  const int tid = threadIdx.x;
  const int lane = tid & 63;
  const int wid = tid >> 6;   // 0..3
  const int wr = wid >> 1;    // 0..1
  const int wc = wid & 1;     // 0..1
  const int lo = lane & 31;
  const int hi = lane >> 5;
  const int l7 = lane & 7;
  const int l8 = lane >> 3;
  const long laneA = (long)l8 * lda + ((l7 ^ l8) << 3);
  const long laneB = (long)l8 * ldb + ((l7 ^ l8) << 3);
  int xk[4];
#pragma unroll
  for (int ks = 0; ks < 4; ++ks) xk[ks] = (ks * 2 + hi) ^ l7;

  const long m0 = (long)by * 128;
  const long n0 = (long)bx * 128;
  const _Float16* Ab = A + (long)bz * As + m0 * (long)lda;
  const _Float16* Bb = B + (long)bz * Bs + n0 * (long)ldb;
  C += (long)bz * Cs;

  f32x16 acc[2][2] = {};
  half8_t af[2][4], bf[2][4];

  // ---- prologue: tile 0 -> parity 0
  stage_op(Ab, laneA, lda, 0, smem, wid);
  stage_op(Bb, laneB, ldb, 0, smem + 32768, wid);
  asm volatile("s_waitcnt vmcnt(0)" ::: "memory");
  __builtin_amdgcn_s_barrier();

  for (int t = 0; t < NT; ++t) {
    const int p = t & 1, q = p ^ 1;
    char* sAp = smem + p * 16384;
    char* sBp = smem + 32768 + p * 16384;
    char* sAq = smem + q * 16384;
    char* sBq = smem + 32768 + q * 16384;
    const int u1 = (t + 1 < NT) ? t + 1 : NT - 1;  // tail dup -> dead parity

    // stage t+1 -> q (disjoint from this tile's reads on p)
    stage_op(Ab, laneA, lda, u1, sAq, wid);
    stage_op(Bb, laneB, ldb, u1, sBq, wid);

    // frags from p
    lda_frags(sAp, wr * 64 + lo, xk, af);
    ldb_frags(sBp, wc * 64 + lo, xk, bf);
    asm volatile("s_waitcnt lgkmcnt(0)" ::: "memory");

    __builtin_amdgcn_s_setprio(1);
#pragma unroll
    for (int mp = 0; mp < 2; ++mp)
#pragma unroll
      for (int np = 0; np < 2; ++np)
#pragma unroll
        for (int ks = 0; ks < 4; ++ks)
          acc[mp][np] = __builtin_amdgcn_mfma_f32_32x32x16_f16(
              af[mp][ks], bf[np][ks], acc[mp][np], 0, 0, 0);
    __builtin_amdgcn_s_setprio(0);

    // own stages drained, barrier syncs all waves -> q complete for t+1
    asm volatile("s_waitcnt vmcnt(0)" ::: "memory");
    __builtin_amdgcn_s_barrier();
  }

  // epilogue: 32x32 C/D layout col = lo, row = (e&3) + 8*(e>>2) + 4*hi
#pragma unroll
  for (int mp = 0; mp < 2; ++mp) {
    const int r0 = wr * 64 + mp * 32 + 4 * hi;
#pragma unroll
    for (int np = 0; np < 2; ++np) {
      const int cc = (int)n0 + wc * 64 + np * 32 + lo;
#pragma unroll
      for (int e = 0; e < 16; ++e) {
        const long row = m0 + r0 + (e & 3) + 8 * (e >> 2);
        float v = acc[mp][np][e];
        if constexpr (BIAS == 1) v += bias[bz * biasStride + cc];
        if constexpr (BIAS == 2) v += bias[(int)row];
        C[row * (long)ldc + cc] = (OT)v;
      }
    }
  }
}

// ===================== auxiliary kernels =====================

// fp32 -> fp16, one float4 chunk per thread, 3 tensors of 16M floats each.
__global__ __launch_bounds__(256) void convert_x(const float* __restrict__ x0,
                                                 const float* __restrict__ x1,
                                                 const float* __restrict__ x2,
                                                 _Float16* __restrict__ out) {
  int i = blockIdx.x * 256 + threadIdx.x;  // 12582912 chunks total
  int t = i >> 22;                         // 4194304 chunks per tensor
  int j = i & 4194303;
  const float* src = (t == 0) ? x0 : (t == 1) ? x1 : x2;
  floatx4 v = ((const floatx4*)src)[j];
  half4_t h = {(_Float16)v[0], (_Float16)v[1], (_Float16)v[2], (_Float16)v[3]};
  ((half4_t*)out)[i] = h;
}

__global__ __launch_bounds__(256) void convert_w(const float* __restrict__ Wq,
                                                 const float* __restrict__ Wk,
                                                 const float* __restrict__ Wv,
                                                 _Float16* __restrict__ out) {
  int i = blockIdx.x * 256 + threadIdx.x;  // 786432 chunks total
  int t = i >> 18;                         // 262144 chunks per tensor
  int j = i & 262143;
  const float* src = (t == 0) ? Wq : (t == 1) ? Wk : Wv;
  floatx4 v = ((const floatx4*)src)[j];
  half4_t h = {(_Float16)v[0], (_Float16)v[1], (_Float16)v[2], (_Float16)v[3]};
  ((half4_t*)out)[i] = h;
}

__global__ __launch_bounds__(256) void pack_bias(const float* __restrict__ bq,
                                                 const float* __restrict__ bk,
                                                 const float* __restrict__ bv,
                                                 float* __restrict__ out) {
  int b = blockIdx.x;
  const float* src = (b == 0) ? bq : (b == 1) ? bk : bv;
  ((floatx4*)out)[b * 256 + threadIdx.x] =
      ((const floatx4*)src)[threadIdx.x];
}

// Row softmax over 1024 fp16 scores, fp32 math, fp16 result in place.
__global__ __launch_bounds__(256) void softmax_rows_h(_Float16* __restrict__ S) {
  long row = blockIdx.x;
  _Float16* Sr = S + row * 1024;
  int tid = threadIdx.x, lane = tid & 63, wid = tid >> 6;
  half4_t x = ((const half4_t*)Sr)[tid];
  float x0 = x[0], x1 = x[1], x2 = x[2], x3 = x[3];
  float mx = fmaxf(fmaxf(x0, x1), fmaxf(x2, x3));
#pragma unroll
  for (int off = 32; off > 0; off >>= 1) mx = fmaxf(mx, __shfl_xor(mx, off));
  __shared__ float redm[4];
  if (lane == 0) redm[wid] = mx;
  __syncthreads();
  mx = fmaxf(fmaxf(redm[0], redm[1]), fmaxf(redm[2], redm[3]));
  float e0 = __expf(x0 - mx), e1 = __expf(x1 - mx);
  float e2 = __expf(x2 - mx), e3 = __expf(x3 - mx);
  float s = e0 + e1 + e2 + e3;
#pragma unroll
  for (int off = 32; off > 0; off >>= 1) s += __shfl_xor(s, off);
  __shared__ float reds[4];
  if (lane == 0) reds[wid] = s;
  __syncthreads();
  s = reds[0] + reds[1] + reds[2] + reds[3];
  float inv = 1.0f / s;
  half4_t h = {(_Float16)(e0 * inv), (_Float16)(e1 * inv),
               (_Float16)(e2 * inv), (_Float16)(e3 * inv)};
  ((half4_t*)Sr)[tid] = h;
}

extern "C" void kernel_launch(void* const* d_in, const int* in_sizes, int n_in,
                              void* d_out, int out_size, void* d_ws,
                              size_t ws_size, hipStream_t stream) {
  (void)in_sizes; (void)n_in; (void)out_size; (void)ws_size;
  const float* meme  = (const float*)d_in[0];
  const float* text  = (const float*)d_in[1];
  const float* emoji = (const float*)d_in[2];
  const float* Wq = (const float*)d_in[3];
  const float* bq = (const float*)d_in[4];
  const float* Wk = (const float*)d_in[5];
  const float* bk = (const float*)d_in[6];
  const float* Wv = (const float*)d_in[7];
  const float* bv = (const float*)d_in[8];

  const long MB = 1024 * 1024;
  char* ws = (char*)d_ws;
  // [0,6) MB:    hWq/hWk/hWv fp16 (contiguous, stride 1M halves)
  // [6,7):       packed bias 3*1024 fp32
  // [7,39) MB:   meme_h  -> dead after QK GEMM -> reused as S (fp16, 32MB)
  // [39,71) MB:  text_h  -> dead after QK GEMM -> reused as Vt (fp16, 32MB)
  // [71,103) MB: emoji_h -> dead after Vt GEMM
  // [103,135):   Qh fp16   [135,167): Kh fp16
  _Float16* hWq = (_Float16*)ws;
  float* pbias  = (float*)(ws + 6 * MB);
  _Float16* mh  = (_Float16*)(ws + 7 * MB);
  _Float16* th  = (_Float16*)(ws + 39 * MB);
  _Float16* eh  = (_Float16*)(ws + 71 * MB);
  _Float16* Qh  = (_Float16*)(ws + 103 * MB);
  _Float16* Kh  = (_Float16*)(ws + 135 * MB);
  _Float16* S   = mh;  // aliases meme_h (dead by then)
  _Float16* Vt  = th;  // aliases text_h (dead by then)
  _Float16* hWv = hWq + 2 * MB;

  dim3 blk(256);
  convert_w<<<3072, blk, 0, stream>>>(Wq, Wk, Wv, hWq);
  pack_bias<<<3, blk, 0, stream>>>(bq, bk, bv, pbias);
  convert_x<<<49152, blk, 0, stream>>>(meme, text, emoji, mh);

  // Q,K projections batched (z=2, contiguous workspace): M=16384, N=1024.
  gemm128<_Float16, 1, 8, 128><<<dim3(2048), blk, 0, stream>>>(
      mh, 16777216, 1024, hWq, 1048576, 1024, Qh, 16777216, 1024, pbias, 1024);
  // Vt[a, b*L+l] = sum_h Wv[a,h]*emoji[b,l,h] + bv[a]  (V transposed)
  gemm128<_Float16, 2, 128, 8><<<dim3(1024), blk, 0, stream>>>(
      hWv, 0, 1024, eh, 0, 1024, Vt, 0, 16384, pbias + 2048, 0);
  // S[b] = Q[b] @ K[b]^T -> fp16. per-batch 1024x1024, z=16.
  gemm128<_Float16, 0, 8, 8><<<dim3(1024), blk, 0, stream>>>(
      Qh, 1048576, 1024, Kh, 1048576, 1024, S, 1048576, 1024, nullptr, 0);
  // softmax rows, fp16 in place
  softmax_rows_h<<<16384, blk, 0, stream>>>(S);
  // O[b] = P[b] @ V[b] via Vt: C[q,a] = sum_k P[q,k] * Vt[a, b*1024+k]
  gemm128<float, 0, 8, 8><<<dim3(1024), blk, 0, stream>>>(
      S, 1048576, 1024, Vt, 1024, 16384, (float*)d_out, 1048576, 1024,
      nullptr, 0);
}